// Round 8
// baseline (157.686 us; speedup 1.0000x reference)
//
#include <hip/hip_runtime.h>
#include <hip/hip_bf16.h>

// DCNv2 forward: B=2, C=256, H=W=96, O=256, K=3x3, stride=1, pad=1, dil=1.
// Pipeline:
//  K1 prep     : (a) input NCHW fp32 -> NHWC bf16,
//                (b) weight -> bf16 stream order wt[kk][osub][cc][lane][8]
//  K2 dcn_main : per tap: fill fragment-order LDS col tile, then 16 MFMA
//                chunks with register weight-ring (depth 3).
//
// R7 lesson: <2 waves/SIMD exposed every stall; intra-wave pipelining can't
// fix that (a wave blocks at s_waitcnt regardless). R6's cross-block wave
// coverage was the real hiding mechanism. R8 = R6 grid shape (576 x 256thr,
// 32-s x 256-O) with: fragment-order LDS colB[g][n][8] (conflict-free, imm
// offsets, single buffer), weight ring depth 3 issued at tap top, 25.6 KB
// LDS + launch_bounds(256,4) so every SIMD holds 2-3 independent waves.

#define Hh 96
#define Ww 96
#define Cc 256
#define Oo 256
#define Bb 2
#define Kk 9
#define Ss (Hh * Ww)          // 9216
#define CKTOT (Cc * Kk)       // 2304

typedef __bf16 bf16x8 __attribute__((ext_vector_type(8)));
typedef __bf16 bf16x2v __attribute__((ext_vector_type(2)));
typedef float f32x16 __attribute__((ext_vector_type(16)));
typedef float f32x2 __attribute__((ext_vector_type(2)));

__device__ __forceinline__ f32x2 up2(unsigned u) {
  f32x2 r;
  r.x = __uint_as_float(u << 16);
  r.y = __uint_as_float(u & 0xffff0000u);
  return r;
}

// barrier with LDS drain only — in-flight global loads cross freely.
// simm16 0xC07F = lgkmcnt(0), expcnt(0), vmcnt(63)=no-wait.
__device__ __forceinline__ void barrier_lgkm() {
  asm volatile("" ::: "memory");
  __builtin_amdgcn_s_waitcnt(0xC07F);
  __builtin_amdgcn_s_barrier();
  asm volatile("" ::: "memory");
}

// ---------------- K1: merged prep (unchanged from R7) ----------------
// blocks [0,1152)    : transpose NCHW fp32 -> NHWC bf16
// blocks [1152,3456) : weight repack to stream order:
//   wt[kk][osub][cc][lane][j]: o = osub*32 + (lane&31), ch = cc*16 + (lane>>5)*8 + j
__global__ __launch_bounds__(256) void prep(const float* __restrict__ inp,
                                            const float* __restrict__ wsrc,
                                            __bf16* __restrict__ it,
                                            __bf16* __restrict__ wt) {
  __shared__ float tile[64][65];
  const int bx = blockIdx.x;
  const int tid = threadIdx.x;

  if (bx < 1152) {
    const int hw0 = (bx % 144) * 64;
    const int c0 = ((bx / 144) & 3) * 64;
    const int b = bx / 576;
    const int hw_l = tid & 63, cr = tid >> 6;
    const float* src = inp + ((size_t)(b * Cc + c0) * Ss) + hw0;
#pragma unroll
    for (int r = 0; r < 16; ++r) {
      int c_l = r * 4 + cr;
      tile[c_l][hw_l] = src[(size_t)c_l * Ss + hw_l];
    }
    __syncthreads();
    const int cp = (tid & 31) * 2, hr = tid >> 5;
    __bf16* dst = it + ((size_t)(b * Ss + hw0) * Cc) + c0;
#pragma unroll
    for (int r = 0; r < 8; ++r) {
      int hw_s = r * 8 + hr;
      bf16x2v p;
      p.x = (__bf16)tile[cp][hw_s];
      p.y = (__bf16)tile[cp + 1][hw_s];
      *(bf16x2v*)(dst + (size_t)hw_s * Cc + cp) = p;
    }
  } else {
    int i = (bx - 1152) * 256 + tid;  // i < Oo*CKTOT = 589824
    int j = i & 7;
    int l = (i >> 3) & 63;
    int cc = (i >> 9) & 15;
    int osub = (i >> 13) & 7;
    int kk = i >> 16;
    int o = osub * 32 + (l & 31);
    int ch = cc * 16 + ((l >> 5) << 3) + j;
    wt[i] = (__bf16)wsrc[(o * Cc + ch) * Kk + kk];
  }
}

// ---------------- K2: fused sample + GEMM ----------------
// grid (288, 2): x = 32-s tile (XCD-swizzled), y = batch.
// 256 thr = 4 waves; wave wv: o in [wv*64, wv*64+64) as osub pair (2wv,2wv+1).
__global__ __launch_bounds__(256, 4) void dcn_main(
    const __bf16* __restrict__ it,     // [B][S][C] bf16
    const __bf16* __restrict__ wt,     // stream-order weights
    const float* __restrict__ offset,  // [B][18][S]
    const float* __restrict__ mask,    // [B][9][S]
    const float* __restrict__ bias,    // [O]
    float* __restrict__ out)           // [B][O][S]
{
  // fragment-order column tile: colB[g:32][n:32][8], g = chunk*2 + hi.
  // value at (s = s0+n, ch = g*8+j). 16 KB, single buffer.
  __shared__ __bf16 colB[32 * 32 * 8];
  __shared__ int4 pa9[9][32];    // corner BYTE offsets into NHWC image
  __shared__ float4 pw9[9][32];  // corner weights (mask+validity folded)

  const int tid = threadIdx.x;
  // XCD swizzle: XCD j gets 36 contiguous 32-s tiles.
  const int tile = (blockIdx.x & 7) * 36 + (blockIdx.x >> 3);
  const int s0 = tile * 32;
  const int b = blockIdx.y;
  const int lane = tid & 63;
  const int wv = tid >> 6;
  const int sB = lane & 31;
  const int hi = lane >> 5;
  const int fs = tid & 31;                               // fill: n (s-col)
  const int gb = ((tid >> 5) & 1) + ((tid >> 6) << 1);   // fill: granule base 0..7

  const char* itb = (const char*)(it + (size_t)b * Ss * Cc);

  // ---- bilinear params for all 9 taps up front ----
  for (int idx = tid; idx < 9 * 32; idx += 256) {
    int kk = idx >> 5;
    int sl = idx & 31;
    int s = s0 + sl;
    int ho = s / Ww;
    int wo = s - ho * Ww;
    float dy = offset[((size_t)(b * 18 + 2 * kk)) * Ss + s];
    float dx = offset[((size_t)(b * 18 + 2 * kk + 1)) * Ss + s];
    float m = mask[((size_t)(b * 9 + kk)) * Ss + s];
    float y = (float)(ho - 1 + kk / 3) + dy;
    float x = (float)(wo - 1 + kk % 3) + dx;
    float fy = floorf(y), fx = floorf(x);
    int y0 = (int)fy, x0 = (int)fx;
    float wy = y - fy, wx = x - fx;
    int y1 = y0 + 1, x1 = x0 + 1;
    float vy0 = (y0 >= 0 && y0 < Hh) ? 1.f : 0.f;
    float vy1 = (y1 >= 0 && y1 < Hh) ? 1.f : 0.f;
    float vx0 = (x0 >= 0 && x0 < Ww) ? 1.f : 0.f;
    float vx1 = (x1 >= 0 && x1 < Ww) ? 1.f : 0.f;
    int y0c = min(max(y0, 0), Hh - 1), y1c = min(max(y1, 0), Hh - 1);
    int x0c = min(max(x0, 0), Ww - 1), x1c = min(max(x1, 0), Ww - 1);
    pa9[kk][sl] = make_int4((y0c * Ww + x0c) << 9, (y0c * Ww + x1c) << 9,
                            (y1c * Ww + x0c) << 9, (y1c * Ww + x1c) << 9);
    pw9[kk][sl] = make_float4(m * (1.f - wy) * (1.f - wx) * vy0 * vx0,
                              m * (1.f - wy) * wx * vy0 * vx1,
                              m * wy * (1.f - wx) * vy1 * vx0,
                              m * wy * wx * vy1 * vx1);
  }
  __syncthreads();

  f32x16 acc0, acc1;
#pragma unroll
  for (int j = 0; j < 16; ++j) { acc0[j] = 0.f; acc1[j] = 0.f; }

  for (int kk = 0; kk < Kk; ++kk) {
    if (kk) barrier_lgkm();  // colB reuse: prev compute fully consumed

    // ---- weight ring (depth 3) issued first: ~full-fill-phase lead time ----
    // streams: osub = 2wv (pA), 2wv+1 (pB2); chunk stride 512 elems.
    const __bf16* pA = wt + (((size_t)(kk * 8 + wv * 2) * 16) << 9) + lane * 8;
    const __bf16* pB2 = pA + (16 << 9);
    bf16x8 WA0 = *(const bf16x8*)(pA);
    bf16x8 WB0 = *(const bf16x8*)(pB2);
    bf16x8 WA1 = *(const bf16x8*)(pA + 512);
    bf16x8 WB1 = *(const bf16x8*)(pB2 + 512);
    bf16x8 WA2 = *(const bf16x8*)(pA + 1024);
    bf16x8 WB2 = *(const bf16x8*)(pB2 + 1024);

    // ---- fill: 4 granules/thread, 2-granule load bursts ----
    {
      int4 a = pa9[kk][fs];
      float4 wq = pw9[kk][fs];
#pragma unroll
      for (int half = 0; half < 2; ++half) {
        uint4 D[2][4];
#pragma unroll
        for (int q = 0; q < 2; ++q) {
          int g = gb + (half * 2 + q) * 8;
          const char* p = itb + g * 16;
          D[q][0] = *(const uint4*)(p + a.x);
          D[q][1] = *(const uint4*)(p + a.y);
          D[q][2] = *(const uint4*)(p + a.z);
          D[q][3] = *(const uint4*)(p + a.w);
        }
#pragma unroll
        for (int q = 0; q < 2; ++q) {
          int g = gb + (half * 2 + q) * 8;
          unsigned u0[4] = {D[q][0].x, D[q][0].y, D[q][0].z, D[q][0].w};
          unsigned u1[4] = {D[q][1].x, D[q][1].y, D[q][1].z, D[q][1].w};
          unsigned u2[4] = {D[q][2].x, D[q][2].y, D[q][2].z, D[q][2].w};
          unsigned u3[4] = {D[q][3].x, D[q][3].y, D[q][3].z, D[q][3].w};
          bf16x8 rv;
#pragma unroll
          for (int w = 0; w < 4; ++w) {
            f32x2 r = up2(u0[w]) * wq.x + up2(u1[w]) * wq.y +
                      up2(u2[w]) * wq.z + up2(u3[w]) * wq.w;
            rv[2 * w] = (__bf16)r.x;
            rv[2 * w + 1] = (__bf16)r.y;
          }
          *(bf16x8*)&colB[(g * 32 + fs) * 8] = rv;
        }
      }
    }
    barrier_lgkm();  // fill visible; weight ring still streaming in

    // ---- compute: 16 chunks, B 1-deep + W-ring 3-deep lookahead ----
    const __bf16* bp = &colB[(hi * 32 + sB) * 8];  // + c*512 elems, all imm
    bf16x8 Bc = *(const bf16x8*)bp;
#pragma unroll
    for (int c = 0; c < 16; ++c) {
      bf16x8 Bn, WAn, WBn;
      if (c < 15) Bn = *(const bf16x8*)(bp + (c + 1) * 512);
      if (c < 13) {
        WAn = *(const bf16x8*)(pA + (c + 3) * 512);
        WBn = *(const bf16x8*)(pB2 + (c + 3) * 512);
      }
      acc0 = __builtin_amdgcn_mfma_f32_32x32x16_bf16(WA0, Bc, acc0, 0, 0, 0);
      acc1 = __builtin_amdgcn_mfma_f32_32x32x16_bf16(WB0, Bc, acc1, 0, 0, 0);
      WA0 = WA1; WB0 = WB1;
      WA1 = WA2; WB1 = WB2;
      if (c < 13) { WA2 = WAn; WB2 = WBn; }
      if (c < 15) Bc = Bn;
    }
  }

  // ---- epilogue: direct store with bias ----
  // D mapping (32x32): col(s)=sB, row(o-off)=(r&3)+8*(r>>2)+4*hi
  float* ob = out + (size_t)b * Oo * Ss + s0 + sB;
#pragma unroll
  for (int os = 0; os < 2; ++os) {
#pragma unroll
    for (int r = 0; r < 16; ++r) {
      int o = wv * 64 + os * 32 + (r & 3) + 8 * (r >> 2) + 4 * hi;
      float v = (os ? acc1[r] : acc0[r]) + bias[o];
      ob[(size_t)o * Ss] = v;
    }
  }
}

extern "C" void kernel_launch(void* const* d_in, const int* in_sizes, int n_in,
                              void* d_out, int out_size, void* d_ws, size_t ws_size,
                              hipStream_t stream) {
  (void)in_sizes; (void)n_in; (void)out_size; (void)ws_size;
  const float* inp = (const float*)d_in[0];
  const float* offset = (const float*)d_in[1];
  const float* mask = (const float*)d_in[2];
  const float* weight = (const float*)d_in[3];
  const float* bias = (const float*)d_in[4];
  float* out = (float*)d_out;

  __bf16* it = (__bf16*)d_ws;                                      // 9,437,184 B
  __bf16* wt = (__bf16*)((char*)d_ws + (size_t)Bb * Ss * Cc * 2);  // 1,179,648 B

  prep<<<3456, 256, 0, stream>>>(inp, weight, it, wt);
  dcn_main<<<dim3(288, Bb), 256, 0, stream>>>(it, wt, offset, mask, bias, out);
}

// Round 9
// 131.097 us; speedup vs baseline: 1.2028x; 1.2028x over previous
//
#include <hip/hip_runtime.h>
#include <hip/hip_bf16.h>

// DCNv2 forward: B=2, C=256, H=W=96, O=256, K=3x3, stride=1, pad=1, dil=1.
// Pipeline:
//  K1 prep     : (a) input NCHW fp32 -> NHWC bf16,
//                (b) weight -> bf16 stream order wt[kk][osub][cc][lane][8]
//  K2 dcn_main : per tap: exact-line burst fill into dbuf fragment-order LDS,
//                ONE lgkm barrier, compute 16 chunks with W-ring(8)+B-ring(4).
//
// R8 lesson: single-buffer (2 barriers/tap) phase-lockstepped the block ->
// 83us. R6's 1-barrier + dbuf allowed cross-wave slip -> 55us. New model:
// L2-request-rate (~1 line/cyc/CU) floor ~26-35us; R6 wasted 2x on fill
// lines and exposed ~180cyc/chunk weight latency (1-deep lookahead).
// R9: exact-line fill (each 64B line requested once), W-ring depth 8,
// B-ring depth 4, 8-wave blocks (18 waves/CU), R6 barrier discipline.

#define Hh 96
#define Ww 96
#define Cc 256
#define Oo 256
#define Bb 2
#define Kk 9
#define Ss (Hh * Ww)          // 9216
#define CKTOT (Cc * Kk)       // 2304

typedef __bf16 bf16x8 __attribute__((ext_vector_type(8)));
typedef __bf16 bf16x2v __attribute__((ext_vector_type(2)));
typedef float f32x16 __attribute__((ext_vector_type(16)));
typedef float f32x2 __attribute__((ext_vector_type(2)));

__device__ __forceinline__ f32x2 up2(unsigned u) {
  f32x2 r;
  r.x = __uint_as_float(u << 16);
  r.y = __uint_as_float(u & 0xffff0000u);
  return r;
}

// barrier with LDS drain only — in-flight global loads cross freely.
// simm16 0xC07F = lgkmcnt(0), expcnt(0), vmcnt(63)=no-wait.
__device__ __forceinline__ void barrier_lgkm() {
  asm volatile("" ::: "memory");
  __builtin_amdgcn_s_waitcnt(0xC07F);
  __builtin_amdgcn_s_barrier();
  asm volatile("" ::: "memory");
}

// ---------------- K1: merged prep (unchanged) ----------------
// blocks [0,1152)    : transpose NCHW fp32 -> NHWC bf16
// blocks [1152,3456) : weight repack to stream order:
//   wt[kk][osub][cc][lane][j]: o = osub*32 + (lane&31), ch = cc*16 + (lane>>5)*8 + j
__global__ __launch_bounds__(256) void prep(const float* __restrict__ inp,
                                            const float* __restrict__ wsrc,
                                            __bf16* __restrict__ it,
                                            __bf16* __restrict__ wt) {
  __shared__ float tile[64][65];
  const int bx = blockIdx.x;
  const int tid = threadIdx.x;

  if (bx < 1152) {
    const int hw0 = (bx % 144) * 64;
    const int c0 = ((bx / 144) & 3) * 64;
    const int b = bx / 576;
    const int hw_l = tid & 63, cr = tid >> 6;
    const float* src = inp + ((size_t)(b * Cc + c0) * Ss) + hw0;
#pragma unroll
    for (int r = 0; r < 16; ++r) {
      int c_l = r * 4 + cr;
      tile[c_l][hw_l] = src[(size_t)c_l * Ss + hw_l];
    }
    __syncthreads();
    const int cp = (tid & 31) * 2, hr = tid >> 5;
    __bf16* dst = it + ((size_t)(b * Ss + hw0) * Cc) + c0;
#pragma unroll
    for (int r = 0; r < 8; ++r) {
      int hw_s = r * 8 + hr;
      bf16x2v p;
      p.x = (__bf16)tile[cp][hw_s];
      p.y = (__bf16)tile[cp + 1][hw_s];
      *(bf16x2v*)(dst + (size_t)hw_s * Cc + cp) = p;
    }
  } else {
    int i = (bx - 1152) * 256 + tid;  // i < Oo*CKTOT = 589824
    int j = i & 7;
    int l = (i >> 3) & 63;
    int cc = (i >> 9) & 15;
    int osub = (i >> 13) & 7;
    int kk = i >> 16;
    int o = osub * 32 + (l & 31);
    int ch = cc * 16 + ((l >> 5) << 3) + j;
    wt[i] = (__bf16)wsrc[(o * Cc + ch) * Kk + kk];
  }
}

// ---------------- K2: fused sample + GEMM ----------------
// grid (288, 2): x = 32-s tile (XCD-swizzled), y = batch.
// 512 thr = 8 waves; wave w: o in [w*32, w*32+32); block = 256 O x 32 s.
__global__ __launch_bounds__(512, 4) void dcn_main(
    const __bf16* __restrict__ it,     // [B][S][C] bf16
    const __bf16* __restrict__ wt,     // stream-order weights
    const float* __restrict__ offset,  // [B][18][S]
    const float* __restrict__ mask,    // [B][9][S]
    const float* __restrict__ bias,    // [O]
    float* __restrict__ out)           // [B][O][S]
{
  // fragment-order tap tile, double-buffered. Chunk index = g*32 + n', where
  // g = granule (8ch), n' = n ^ ((g&1)<<2) (parity swizzle -> even bank groups).
  __shared__ __bf16 colB[2][32 * 256];
  __shared__ int4 pa9[9][32];    // corner BYTE offsets into NHWC image
  __shared__ float4 pw9[9][32];  // corner weights (mask+validity folded)

  const int tid = threadIdx.x;
  // XCD swizzle: XCD j gets 36 contiguous 32-s tiles.
  const int tile = (blockIdx.x & 7) * 36 + (blockIdx.x >> 3);
  const int s0 = tile * 32;
  const int b = blockIdx.y;
  const int lane = tid & 63;
  const int w = tid >> 6;             // wave id 0..7 -> osub
  const int sB = lane & 31;
  const int hi = lane >> 5;
  // fill layout: 4 pixels x 16 line-chunks per wave (exact-line coverage)
  const int pp = lane >> 4;           // 0..3
  const int gq = lane & 15;           // 16B chunk within 256B half-row
  const int nf = w * 4 + pp;          // pixel (s within tile) 0..31
  const int swz = (nf ^ ((gq & 1) << 2));  // write swizzle, const per thread

  const char* itb = (const char*)(it + (size_t)b * Ss * Cc);

  // ---- bilinear params for all 9 taps up front ----
  if (tid < 9 * 32) {
    int kk = tid >> 5;
    int sl = tid & 31;
    int s = s0 + sl;
    int ho = s / Ww;
    int wo = s - ho * Ww;
    float dy = offset[((size_t)(b * 18 + 2 * kk)) * Ss + s];
    float dx = offset[((size_t)(b * 18 + 2 * kk + 1)) * Ss + s];
    float m = mask[((size_t)(b * 9 + kk)) * Ss + s];
    float y = (float)(ho - 1 + kk / 3) + dy;
    float x = (float)(wo - 1 + kk % 3) + dx;
    float fy = floorf(y), fx = floorf(x);
    int y0 = (int)fy, x0 = (int)fx;
    float wy = y - fy, wx = x - fx;
    int y1 = y0 + 1, x1 = x0 + 1;
    float vy0 = (y0 >= 0 && y0 < Hh) ? 1.f : 0.f;
    float vy1 = (y1 >= 0 && y1 < Hh) ? 1.f : 0.f;
    float vx0 = (x0 >= 0 && x0 < Ww) ? 1.f : 0.f;
    float vx1 = (x1 >= 0 && x1 < Ww) ? 1.f : 0.f;
    int y0c = min(max(y0, 0), Hh - 1), y1c = min(max(y1, 0), Hh - 1);
    int x0c = min(max(x0, 0), Ww - 1), x1c = min(max(x1, 0), Ww - 1);
    pa9[kk][sl] = make_int4((y0c * Ww + x0c) << 9, (y0c * Ww + x1c) << 9,
                            (y1c * Ww + x0c) << 9, (y1c * Ww + x1c) << 9);
    pw9[kk][sl] = make_float4(m * (1.f - wy) * (1.f - wx) * vy0 * vx0,
                              m * (1.f - wy) * wx * vy0 * vx1,
                              m * wy * (1.f - wx) * vy1 * vx0,
                              m * wy * wx * vy1 * vx1);
  }
  __syncthreads();

  f32x16 acc;
#pragma unroll
  for (int j = 0; j < 16; ++j) acc[j] = 0.f;

  for (int kk = 0; kk < Kk; ++kk) {
    const int buf = kk & 1;
    // ---- weight ring preload: chunks 0..7 (in flight across fill+barrier) ----
    const __bf16* pW = wt + (((size_t)(kk * 8 + w) * 16) << 9) + (lane << 3);
    bf16x8 Wr[8];
#pragma unroll
    for (int r = 0; r < 8; ++r) Wr[r] = *(const bf16x8*)(pW + r * 512);

    // ---- fill: 8 exact-line corner loads, bilinear, LDS write ----
    {
      int4 a = pa9[kk][nf];
      float4 wq = pw9[kk][nf];
      uint4 D[2][4];
#pragma unroll
      for (int j = 0; j < 2; ++j) {
        const char* p = itb + (j * 16 + gq) * 16;
        D[j][0] = *(const uint4*)(p + a.x);
        D[j][1] = *(const uint4*)(p + a.y);
        D[j][2] = *(const uint4*)(p + a.z);
        D[j][3] = *(const uint4*)(p + a.w);
      }
#pragma unroll
      for (int j = 0; j < 2; ++j) {
        unsigned u0[4] = {D[j][0].x, D[j][0].y, D[j][0].z, D[j][0].w};
        unsigned u1[4] = {D[j][1].x, D[j][1].y, D[j][1].z, D[j][1].w};
        unsigned u2[4] = {D[j][2].x, D[j][2].y, D[j][2].z, D[j][2].w};
        unsigned u3[4] = {D[j][3].x, D[j][3].y, D[j][3].z, D[j][3].w};
        bf16x8 rv;
#pragma unroll
        for (int d = 0; d < 4; ++d) {
          f32x2 r = up2(u0[d]) * wq.x + up2(u1[d]) * wq.y +
                    up2(u2[d]) * wq.z + up2(u3[d]) * wq.w;
          rv[2 * d] = (__bf16)r.x;
          rv[2 * d + 1] = (__bf16)r.y;
        }
        int g = j * 16 + gq;
        *(bf16x8*)&colB[buf][g * 256 + swz * 8] = rv;
      }
    }
    barrier_lgkm();  // LDS visible; ring + nothing else drained (vmcnt free)

    // ---- compute: 16 chunks, W-ring(8) + B-ring(4) ----
    const __bf16* bp = &colB[buf][hi * 256 + ((sB ^ (hi << 2)) << 3)];
    bf16x8 Br[4];
#pragma unroll
    for (int r = 0; r < 4; ++r) Br[r] = *(const bf16x8*)(bp + r * 512);
#pragma unroll
    for (int c = 0; c < 16; ++c) {
      bf16x8 Bn, Wn;
      if (c < 12) Bn = *(const bf16x8*)(bp + (c + 4) * 512);
      if (c < 8) Wn = *(const bf16x8*)(pW + (c + 8) * 512);
      acc = __builtin_amdgcn_mfma_f32_32x32x16_bf16(Wr[c & 7], Br[c & 3], acc, 0, 0, 0);
      if (c < 12) Br[c & 3] = Bn;
      if (c < 8) Wr[c & 7] = Wn;
    }
  }

  // ---- epilogue: direct store with bias ----
  // D mapping (32x32): col(s)=sB, row(o-off)=(r&3)+8*(r>>2)+4*hi
  float* ob = out + (size_t)b * Oo * Ss + s0 + sB;
#pragma unroll
  for (int r = 0; r < 16; ++r) {
    int o = w * 32 + (r & 3) + 8 * (r >> 2) + 4 * hi;
    ob[(size_t)o * Ss] = acc[r] + bias[o];
  }
}

extern "C" void kernel_launch(void* const* d_in, const int* in_sizes, int n_in,
                              void* d_out, int out_size, void* d_ws, size_t ws_size,
                              hipStream_t stream) {
  (void)in_sizes; (void)n_in; (void)out_size; (void)ws_size;
  const float* inp = (const float*)d_in[0];
  const float* offset = (const float*)d_in[1];
  const float* mask = (const float*)d_in[2];
  const float* weight = (const float*)d_in[3];
  const float* bias = (const float*)d_in[4];
  float* out = (float*)d_out;

  __bf16* it = (__bf16*)d_ws;                                      // 9,437,184 B
  __bf16* wt = (__bf16*)((char*)d_ws + (size_t)Bb * Ss * Cc * 2);  // 1,179,648 B

  prep<<<3456, 256, 0, stream>>>(inp, weight, it, wt);
  dcn_main<<<dim3(288, Bb), 512, 0, stream>>>(it, wt, offset, mask, bias, out);
}